// Round 12
// baseline (7123.586 us; speedup 1.0000x reference)
//
#include <hip/hip_runtime.h>
#include <math.h>

#define LL 256
#define BB 256
#define HH 256
#define CC 16
#define YY 32
#define HC (HH*CC)     // 4096
#define NSTEP (LL-1)   // 255
#define TPB 1024
#define NG 16          // batch groups
#define GB 16          // batches per group
#define NSL 16         // slices (sibling blocks) per group; 256 W2 cols each

// fast tanh (k_out ONLY — scan uses libm tanhf: scan amplifies tanh error
// ~1e4x through 255 steps).
__device__ __forceinline__ float fast_tanh(float x) {
    float e = __expf(2.0f * x);
    return 1.0f - 2.0f / (e + 1.0f);
}

// coherence-point (device-coherent) access — bypasses non-coherent per-XCD
// L2s. ONLY cross-block exchange primitive.
__device__ __forceinline__ float2 ld_coh2(const float* p) {
    union { unsigned long long u; float2 f; } cv;
    cv.u = __hip_atomic_load((const unsigned long long*)p,
                             __ATOMIC_RELAXED, __HIP_MEMORY_SCOPE_AGENT);
    return cv.f;
}
__device__ __forceinline__ void st_coh(float* p, float v) {
    __hip_atomic_store(p, v, __ATOMIC_RELAXED, __HIP_MEMORY_SCOPE_AGENT);
}

// 16-way sibling barrier, monotonic per-group counter (no reset).
// RACE FIX (r12): arrival is a RELEASE fetch_add — architecturally guarantees
// all of this block's prior stores (hid/z publishes) are device-visible
// before the arrival is visible. Poll is ACQUIRE. Previously relied on
// __syncthreads' vmcnt drain only, which does not prove L3 arrival; r10/r11
// (identical binaries) gave different absmax => nondeterministic staleness.
__device__ __forceinline__ void bg_barrier(unsigned* cnt, unsigned target) {
    __syncthreads();
    if (threadIdx.x == 0) {
        __hip_atomic_fetch_add(cnt, 1u, __ATOMIC_RELEASE, __HIP_MEMORY_SCOPE_AGENT);
        while (__hip_atomic_load(cnt, __ATOMIC_ACQUIRE, __HIP_MEMORY_SCOPE_AGENT) < target)
            __builtin_amdgcn_s_sleep(2);
    }
    __syncthreads();
}

// ---------------------------------------------------------------------------
// persistent scan: 256 blocks = 16 bg x 16 sl, 1024 threads (1 block/CU).
// block (bg, sl): batches b0..b0+15, W2 cols n0..n0+255 (h-slice of 16).
// Per step: A: hid tile(16b x 16h own slice) -> publish; bar;
//           stage full hid(256j x 16b); B: g(16b x 256c) = hid @ W2-slice;
//           dz (c-reduce); z[k+1] h-slice; bar.
// W2 traffic: 256 KB/block/step (2x reuse vs r6's 512 KB).
// ---------------------------------------------------------------------------
__global__ void __launch_bounds__(TPB)
k_scan(const float* __restrict__ us, const float* __restrict__ W1,
       const float* __restrict__ b1, const float* __restrict__ W2,
       const float* __restrict__ b2, float* __restrict__ zs,
       float* __restrict__ hidX, unsigned* __restrict__ barG) {
    __shared__ float smem[4*GB*256 + GB*260 + 4096 + 16*260 + 256 + 256 + 16];
    float* psum  = smem;                          // [4][16][256] 64 KB (B)
    float* pa    = smem;                          // alias [4][256] (A partials)
    float* z_locB= smem + 4*GB*256;               // [16 b][260]  16.6 KB
    float* hidT  = z_locB + GB*260;               // flat [256 j][16 b] 16 KB
    float* w1sT  = hidT + 4096;                   // [16 h][260]  16.6 KB
    float* b2s   = w1sT + 16*260;                 // [256]
    float* dvs   = b2s + 256;                     // [16 b][16 c]
    float* b1s   = dvs + 256;                     // [16]

    const int t  = threadIdx.x;
    const int bg = blockIdx.x >> 4;               // 0..15
    const int sl = blockIdx.x & 15;               // 0..15
    const int b0 = bg * GB;
    const int n0 = sl * 256;                      // global W2 col base
    unsigned* cnt = barG + bg * 64;               // 256-B line per group

    // ---- one-time preload: W1 slice (transposed), biases ----
    for (int i = t; i < 16 * 256; i += TPB) {
        int hl = i >> 8, j = i & 255;
        w1sT[hl * 260 + j] = W1[(size_t)j * HH + sl * 16 + hl];
    }
    for (int i = t; i < 256; i += TPB) b2s[i] = b2[n0 + i];
    if (t < 16) b1s[t] = b1[sl * 16 + t];
    __syncthreads();

    // thread roles
    const int o   = t & 255;                      // A out: ha=o>>4, ba=o&15
    const int jq  = t >> 8;                       // j-split 0..3 (A and B)
    const int col = t & 255;                      // B/dz local column
    const int bq0 = (t >> 8) << 2;                // dz batch base (4 per)

    for (int k = 0; k < NSTEP; k++) {
        const size_t zk = (size_t)k * (BB * HH);

        // ---- stage z (coherent 8B pairs, dense) + dvs ----
        #pragma unroll
        for (int rep = 0; rep < 2; rep++) {
            int p = t + rep * 1024;               // pair id 0..2047
            int b = p >> 7, off = (p & 127) << 1;
            float2 v = ld_coh2(&zs[zk + (size_t)(b0 + b) * HH + off]);
            *(float2*)&z_locB[b * 260 + off] = v; // stride-2: free
        }
        if (t < GB * CC) {
            int b = t >> 4, c = t & 15;
            int kk = (k < 1) ? 1 : k;
            float v = 1.0f;                       // c==0: ts diff == 1
            if (c > 0)
                v = us[((size_t)kk * BB + b0 + b) * (CC - 1) + c - 1]
                  - us[((size_t)(kk - 1) * BB + b0 + b) * (CC - 1) + c - 1];
            dvs[t] = v;
        }
        __syncthreads();

        // ---- phase A: hid tile (16b x 16h own slice), j-split 4 x 64 ----
        {
            const int ha = o >> 4, ba = o & 15;
            const float* wp = &w1sT[ha * 260 + jq * 64];
            const float* zp = &z_locB[ba * 260 + jq * 64];
            float acc = 0.f;
            #pragma unroll
            for (int j4 = 0; j4 < 64; j4 += 4) {
                float4 w = *(const float4*)&wp[j4];
                float4 z = *(const float4*)&zp[j4];
                acc += w.x * z.x + w.y * z.y + w.z * z.z + w.w * z.w;
            }
            pa[jq * 256 + o] = acc;               // lane-stride 1
        }
        __syncthreads();
        if (t < 256) {                            // tree-reduce 4, relu, publish
            int ha = t >> 4, ba = t & 15;
            float s = (pa[t] + pa[256 + t]) + (pa[512 + t] + pa[768 + t])
                    + b1s[ha];
            st_coh(&hidX[bg * 4096 + (sl * 16 + ha) * 16 + ba], fmaxf(s, 0.f));
        }
        bg_barrier(cnt, 16u * (2u * (unsigned)k + 1u));  // hid complete

        // ---- stage full hidT (flat [j][16 b], coherent 8B dense) ----
        #pragma unroll
        for (int rep = 0; rep < 2; rep++) {
            int p = t + rep * 1024;               // pair id 0..2047
            float2 v = ld_coh2(&hidX[bg * 4096 + (p << 1)]);
            *(float2*)&hidT[p << 1] = v;          // stride-2: free
        }
        __syncthreads();

        // ---- phase B: hid(16x256) @ W2-slice(256x256); thread: 64 j x 16 b x 1 c ----
        {
            float acc[GB];
            #pragma unroll
            for (int b = 0; b < GB; b++) acc[b] = 0.f;
            const float* w2p = &W2[(size_t)(jq * 64) * HC + n0 + col];
            const float* hp  = &hidT[(jq * 64) * GB];
            #pragma unroll 4
            for (int j = 0; j < 64; j++) {
                float w  = w2p[(size_t)j * HC];               // coalesced
                float4 hA = *(const float4*)&hp[j * GB];      // bcast
                float4 hB = *(const float4*)&hp[j * GB + 4];  // bcast
                float4 hC = *(const float4*)&hp[j * GB + 8];  // bcast
                float4 hD = *(const float4*)&hp[j * GB + 12]; // bcast
                acc[0]  += hA.x * w; acc[1]  += hA.y * w;
                acc[2]  += hA.z * w; acc[3]  += hA.w * w;
                acc[4]  += hB.x * w; acc[5]  += hB.y * w;
                acc[6]  += hB.z * w; acc[7]  += hB.w * w;
                acc[8]  += hC.x * w; acc[9]  += hC.y * w;
                acc[10] += hC.z * w; acc[11] += hC.w * w;
                acc[12] += hD.x * w; acc[13] += hD.y * w;
                acc[14] += hD.z * w; acc[15] += hD.w * w;
            }
            #pragma unroll
            for (int b = 0; b < GB; b++)
                psum[(jq * GB + b) * 256 + col] = acc[b];  // lane-stride 1
        }
        __syncthreads();

        // ---- dz + z update: lane owns col; tree-sum partials; libm tanhf ----
        {
            #pragma unroll
            for (int q = 0; q < 4; q++) {
                int b = bq0 + q;
                float g = (psum[(0 * GB + b) * 256 + col]
                         + psum[(1 * GB + b) * 256 + col])
                        + (psum[(2 * GB + b) * 256 + col]
                         + psum[(3 * GB + b) * 256 + col]);
                g += b2s[col];
                float v = tanhf(g) * dvs[b * CC + (col & 15)];
                v += __shfl_xor(v, 1);
                v += __shfl_xor(v, 2);
                v += __shfl_xor(v, 4);
                v += __shfl_xor(v, 8);
                if ((col & 15) == 0) {
                    int hg = sl * 16 + (col >> 4);
                    st_coh(&zs[zk + (size_t)(BB * HH) + (size_t)(b0 + b) * HH + hg],
                           z_locB[b * 260 + hg] + v);      // dt == 1
                }
            }
        }
        bg_barrier(cnt, 16u * (2u * (unsigned)k + 2u));    // z[k+1] complete
    }
}

// ---------------------------------------------------------------------------
// out = tanh(z_seq @ dW1 + db1) @ dW2 + db2   (zs natural layout [l*B+b][H])
// grid: L*B/16 = 4096 blocks, 256 threads
// ---------------------------------------------------------------------------
__global__ void k_out(const float* __restrict__ zseq, const float* __restrict__ dW1,
                      const float* __restrict__ db1, const float* __restrict__ dW2,
                      const float* __restrict__ db2, float* __restrict__ out) {
    __shared__ float zt[16][HH];       // 16 KB
    __shared__ float act[16][2 * HH];  // 32 KB
    int r0 = blockIdx.x * 16;
    int t  = threadIdx.x;
    {
        const float4* src = (const float4*)(zseq + (size_t)r0 * HH);
        float4* dst = (float4*)&zt[0][0];
        for (int i = t; i < 1024; i += 256) dst[i] = src[i];
    }
    __syncthreads();
    {   // phase 1: act = tanh(z @ dW1 + db1), 512 cols
        int c0  = (t & 127) * 4;
        int rr0 = (t >> 7) * 8;
        float a[8][4];
        #pragma unroll
        for (int i = 0; i < 8; i++)
            #pragma unroll
            for (int q = 0; q < 4; q++) a[i][q] = 0.f;
        for (int j = 0; j < HH; j++) {
            float4 w = *(const float4*)&dW1[(size_t)j * 2 * HH + c0];
            #pragma unroll
            for (int i = 0; i < 8; i++) {
                float zv = zt[rr0 + i][j];
                a[i][0] += zv * w.x; a[i][1] += zv * w.y;
                a[i][2] += zv * w.z; a[i][3] += zv * w.w;
            }
        }
        float4 bias = *(const float4*)&db1[c0];
        #pragma unroll
        for (int i = 0; i < 8; i++) {
            act[rr0 + i][c0 + 0] = fast_tanh(a[i][0] + bias.x);
            act[rr0 + i][c0 + 1] = fast_tanh(a[i][1] + bias.y);
            act[rr0 + i][c0 + 2] = fast_tanh(a[i][2] + bias.z);
            act[rr0 + i][c0 + 3] = fast_tanh(a[i][3] + bias.w);
        }
    }
    __syncthreads();
    {   // phase 2: out = act @ dW2 + db2
        int rl = t >> 4;
        int y2 = t & 15;
        float o0 = 0.f, o1 = 0.f;
        #pragma unroll 4
        for (int j = 0; j < 2 * HH; j++) {
            float av = act[rl][j];
            float2 w = *(const float2*)&dW2[(size_t)j * YY + y2 * 2];
            o0 += av * w.x; o1 += av * w.y;
        }
        float2 bias = *(const float2*)&db2[y2 * 2];
        out[(size_t)(r0 + rl) * YY + y2 * 2]     = o0 + bias.x;
        out[(size_t)(r0 + rl) * YY + y2 * 2 + 1] = o1 + bias.y;
    }
}

// ---------------------------------------------------------------------------
extern "C" void kernel_launch(void* const* d_in, const int* in_sizes, int n_in,
                              void* d_out, int out_size, void* d_ws, size_t ws_size,
                              hipStream_t stream) {
    const float* us  = (const float*)d_in[1];
    const float* h0  = (const float*)d_in[2];
    const float* W1  = (const float*)d_in[3];
    const float* b1  = (const float*)d_in[4];
    const float* W2  = (const float*)d_in[5];
    const float* b2  = (const float*)d_in[6];
    const float* dW1 = (const float*)d_in[7];
    const float* db1 = (const float*)d_in[8];
    const float* dW2 = (const float*)d_in[9];
    const float* db2 = (const float*)d_in[10];
    float* out = (float*)d_out;

    float* zs   = (float*)d_ws;                        // L*B*H = 64 MB, [l*B+b][h]
    float* hidX = zs + (size_t)LL * BB * HH;           // NG*4096 = 256 KB
    unsigned* barG = (unsigned*)(hidX + NG * 4096);    // 16 x 64 dwords

    hipMemcpyAsync(zs, h0, (size_t)BB * HH * sizeof(float),
                   hipMemcpyDeviceToDevice, stream);
    hipMemsetAsync(barG, 0, NG * 64 * sizeof(unsigned), stream);

    k_scan<<<NG * NSL, TPB, 0, stream>>>(us, W1, b1, W2, b2, zs, hidX, barG);
    k_out<<<LL * BB / 16, 256, 0, stream>>>(zs, dW1, db1, dW2, db2, out);
}